// Round 11
// baseline (148.934 us; speedup 1.0000x reference)
//
#include <hip/hip_runtime.h>
#include <math.h>

#define NN 3072
#define FEAT 512
#define HD 64           // 8 heads x 8 dims
#define NE 100000
#define ALPHA 0.2f
#define CAP 96          // max neighbors per row (mean ~7)
#define CAPP 97         // padded for LDS bank spread
#define AROWS 8         // rows per attn block (8 waves)
#define WH_BLOCKS 768   // wh role: 4 rows per block
#define K5_BLOCKS 2048
#define NPASS 16        // probe replication factor

// K1: byte-identical to round 10 (wh role + pre role fused).
__global__ __launch_bounds__(256) void k_stage1(const float* __restrict__ adj, const float* __restrict__ x,
                                                const float* __restrict__ W, const float* __restrict__ a1,
                                                const float* __restrict__ a2, int* __restrict__ nbr,
                                                int* __restrict__ cnt, float* __restrict__ Wh,
                                                float* __restrict__ s1t, float* __restrict__ s2t) {
    __shared__ float xs[4][FEAT];
    __shared__ float part[4][4][HD];
    __shared__ int   wcnt[4];
    int b = blockIdx.x;
    int tid = threadIdx.x;
    int wid = tid >> 6, lane = tid & 63;

    if (b >= WH_BLOCKS) {
        int i = b - WH_BLOCKS;
        const float4* row4 = (const float4*)&adj[(size_t)i * NN];
        float4 v[3];
        #pragma unroll
        for (int c = 0; c < 3; ++c) v[c] = row4[wid * 192 + c * 64 + lane];
        unsigned long long lmask = (1ull << lane) - 1ull;
        int wc = 0;
        unsigned long long masks[12];
        #pragma unroll
        for (int c = 0; c < 3; ++c) {
            #pragma unroll
            for (int k = 0; k < 4; ++k) {
                float vk = k == 0 ? v[c].x : k == 1 ? v[c].y : k == 2 ? v[c].z : v[c].w;
                unsigned long long m = __ballot(vk > 0.f);
                masks[c * 4 + k] = m;
                wc += __popcll(m);
            }
        }
        if (lane == 0) wcnt[wid] = wc;
        __syncthreads();
        int base = 0;
        #pragma unroll
        for (int w2 = 0; w2 < 4; ++w2) if (w2 < wid) base += wcnt[w2];
        #pragma unroll
        for (int c = 0; c < 3; ++c) {
            #pragma unroll
            for (int k = 0; k < 4; ++k) {
                unsigned long long m = masks[c * 4 + k];
                if ((m >> lane) & 1ull) {
                    int pos = base + __popcll(m & lmask);
                    if (pos < CAP) nbr[i * CAP + pos] = wid * 768 + c * 256 + lane * 4 + k;
                }
                base += __popcll(m);
            }
        }
        if (tid == 0) {
            int tot = wcnt[0] + wcnt[1] + wcnt[2] + wcnt[3];
            cnt[i] = tot < CAP ? tot : CAP;
        }
    } else {
        int n0 = b * 4;
        for (int idx = tid; idx < 512; idx += 256) {
            int r = idx >> 7, fq = idx & 127;
            *(float4*)&xs[r][fq * 4] = ((const float4*)x)[(size_t)(n0 + r) * (FEAT / 4) + fq];
        }
        __syncthreads();
        int fsub = lane >> 4, h = (lane >> 1) & 7, dq = lane & 1;
        const float4* W4 = (const float4*)W;
        int base4 = h * 1024 + dq;
        int f0 = wid * (FEAT / 4);
        float4 acc0 = {0.f,0.f,0.f,0.f}, acc1 = acc0, acc2 = acc0, acc3 = acc0;
        #pragma unroll 4
        for (int f4 = 0; f4 < 32; ++f4) {
            int f = f0 + f4 * 4 + fsub;
            float4 w4 = W4[base4 + f * 2];
            float x0 = xs[0][f], x1 = xs[1][f], x2 = xs[2][f], x3 = xs[3][f];
            acc0.x = fmaf(x0, w4.x, acc0.x); acc0.y = fmaf(x0, w4.y, acc0.y);
            acc0.z = fmaf(x0, w4.z, acc0.z); acc0.w = fmaf(x0, w4.w, acc0.w);
            acc1.x = fmaf(x1, w4.x, acc1.x); acc1.y = fmaf(x1, w4.y, acc1.y);
            acc1.z = fmaf(x1, w4.z, acc1.z); acc1.w = fmaf(x1, w4.w, acc1.w);
            acc2.x = fmaf(x2, w4.x, acc2.x); acc2.y = fmaf(x2, w4.y, acc2.y);
            acc2.z = fmaf(x2, w4.z, acc2.z); acc2.w = fmaf(x2, w4.w, acc2.w);
            acc3.x = fmaf(x3, w4.x, acc3.x); acc3.y = fmaf(x3, w4.y, acc3.y);
            acc3.z = fmaf(x3, w4.z, acc3.z); acc3.w = fmaf(x3, w4.w, acc3.w);
        }
        #define RED4(A) \
            A.x += __shfl_xor(A.x, 16, 64); A.x += __shfl_xor(A.x, 32, 64); \
            A.y += __shfl_xor(A.y, 16, 64); A.y += __shfl_xor(A.y, 32, 64); \
            A.z += __shfl_xor(A.z, 16, 64); A.z += __shfl_xor(A.z, 32, 64); \
            A.w += __shfl_xor(A.w, 16, 64); A.w += __shfl_xor(A.w, 32, 64);
        RED4(acc0) RED4(acc1) RED4(acc2) RED4(acc3)
        #undef RED4
        if (fsub == 0) {
            int o = h * 8 + dq * 4;
            *(float4*)&part[wid][0][o] = acc0;
            *(float4*)&part[wid][1][o] = acc1;
            *(float4*)&part[wid][2][o] = acc2;
            *(float4*)&part[wid][3][o] = acc3;
        }
        __syncthreads();
        int n = n0 + wid;
        float v = part[0][wid][lane] + part[1][wid][lane] + part[2][wid][lane] + part[3][wid][lane];
        Wh[n * HD + lane] = v;
        float t1 = v * a1[lane];
        float t2 = v * a2[lane];
        for (int m = 1; m < 8; m <<= 1) {
            t1 += __shfl_xor(t1, m, 64);
            t2 += __shfl_xor(t2, m, 64);
        }
        if ((lane & 7) == 0) {
            int h2 = lane >> 3;
            s1t[n * 8 + h2] = t1;
            s2t[n * 8 + h2] = t2;
        }
    }
}

// K2 PROBE: attn body x16. rz = cnt[0]>>31 is runtime-0 (cnt in [1,96]); z = rz*ps
// perturbs all addresses symbolically so passes can't be CSE'd; asm keepalive
// prevents DCE. Final pass's p,q (bitwise = pass 0's) are stored.
__global__ __launch_bounds__(512) void k_attn_pq(const float* __restrict__ Wh, const float* __restrict__ s1t,
                                                 const float* __restrict__ s2t, const int* __restrict__ nbr,
                                                 const int* __restrict__ cnt, const float* __restrict__ W1,
                                                 const float* __restrict__ b1, float* __restrict__ P,
                                                 float* __restrict__ Q) {
    __shared__ float W1s[2 * HD][HD];
    __shared__ int   jbuf[AROWS][CAP];
    __shared__ float ebuf[AROWS][8][CAPP];
    __shared__ float es[AROWS][HD];
    int tid = threadIdx.x;
    int wid = tid >> 6;
    int lane = tid & 63;
    int i = blockIdx.x * AROWS + wid;
    int h = lane >> 3, d = lane & 7;
    int rz = (int)(((const unsigned*)cnt)[0] >> 31);   // runtime 0
    float pf = 0.f, qf = 0.f;
    for (int ps = 0; ps < NPASS; ++ps) {
        int z = rz * ps;                               // 0, symbolic per pass
        int iz = i + z;
        int ni = cnt[iz];
        float s1i = s1t[iz * 8 + h];
        for (int k = lane; k < CAP; k += 64)
            if (k < ni) jbuf[wid][k] = nbr[iz * CAP + k];
        for (int idx = tid; idx < 2048; idx += 512)
            ((float4*)W1s)[idx] = ((const float4*)W1)[idx + z];
        __syncthreads();
        float mloc = -INFINITY;
        for (int k = d; k < ni; k += 8) {
            int j = jbuf[wid][k];
            float ev = s1i + s2t[j * 8 + h];
            ev = ev > 0.f ? ev : ALPHA * ev;
            ebuf[wid][h][k] = ev;
            mloc = fmaxf(mloc, ev);
        }
        mloc = fmaxf(mloc, __shfl_xor(mloc, 1, 8));
        mloc = fmaxf(mloc, __shfl_xor(mloc, 2, 8));
        mloc = fmaxf(mloc, __shfl_xor(mloc, 4, 8));
        __syncthreads();
        float denom = 0.f, acc = 0.f;
        for (int k = 0; k < ni; ++k) {
            float p = __expf(ebuf[wid][h][k] - mloc);
            denom += p;
            acc = fmaf(p, Wh[jbuf[wid][k] * HD + lane], acc);
        }
        float o = acc / denom;
        o = o > 0.f ? o : expm1f(o);
        es[wid][lane] = o;
        __syncthreads();
        float p = b1[lane], q = 0.f;
        #pragma unroll 8
        for (int k = 0; k < HD; ++k) {
            float e = es[wid][k];
            p = fmaf(e, W1s[k][lane], p);
            q = fmaf(e, W1s[HD + k][lane], q);
        }
        pf = p; qf = q;
        asm volatile("" :: "v"(pf), "v"(qf));          // keep every pass live
        __syncthreads();                               // drain before next pass re-stages
    }
    P[i * HD + lane] = pf;
    Q[i * HD + lane] = qf;
}

// K3 PROBE: cls gather+compute x16, same rz/keepalive scheme (rz from label[0] in {0,1}).
__global__ __launch_bounds__(256) void k_cls(const float* __restrict__ P, const float* __restrict__ Q,
                                             const int* __restrict__ L, const int* __restrict__ R,
                                             const int* __restrict__ label, const float* __restrict__ W2,
                                             const float* __restrict__ b2, float* __restrict__ partials) {
    int tid = threadIdx.x;
    int sl = tid & 15;
    int g = (blockIdx.x * 256 + tid) >> 4;
    float2 wa = *(const float2*)&W2[(sl * 4 + 0) * 2];
    float2 wb = *(const float2*)&W2[(sl * 4 + 1) * 2];
    float2 wc = *(const float2*)&W2[(sl * 4 + 2) * 2];
    float2 wd = *(const float2*)&W2[(sl * 4 + 3) * 2];
    float b20 = b2[0], b21 = b2[1];
    int rz = (int)(((const unsigned*)label)[0] >> 31);  // runtime 0
    float sumf = 0.f;
    for (int ps = 0; ps < NPASS; ++ps) {
        int z = rz * ps;
        int e0 = g + z, e1 = g + 32768 + z, e2 = g + 65536 + z;
        int ln0 = L[e0], rn0 = R[e0], lb0 = label[e0];
        int ln1 = L[e1], rn1 = R[e1], lb1 = label[e1];
        int ln2 = L[e2], rn2 = R[e2], lb2 = label[e2];
        float4 p0 = *(const float4*)&P[ln0 * HD + sl * 4];
        float4 q0 = *(const float4*)&Q[rn0 * HD + sl * 4];
        float4 p1 = *(const float4*)&P[ln1 * HD + sl * 4];
        float4 q1 = *(const float4*)&Q[rn1 * HD + sl * 4];
        float4 p2 = *(const float4*)&P[ln2 * HD + sl * 4];
        float4 q2 = *(const float4*)&Q[rn2 * HD + sl * 4];
        float v00 = fmaxf(p0.x + q0.x, 0.f), v01 = fmaxf(p0.y + q0.y, 0.f);
        float v02 = fmaxf(p0.z + q0.z, 0.f), v03 = fmaxf(p0.w + q0.w, 0.f);
        float v10 = fmaxf(p1.x + q1.x, 0.f), v11 = fmaxf(p1.y + q1.y, 0.f);
        float v12 = fmaxf(p1.z + q1.z, 0.f), v13 = fmaxf(p1.w + q1.w, 0.f);
        float v20 = fmaxf(p2.x + q2.x, 0.f), v21 = fmaxf(p2.y + q2.y, 0.f);
        float v22 = fmaxf(p2.z + q2.z, 0.f), v23 = fmaxf(p2.w + q2.w, 0.f);
        float t00 = v00 * wa.x + v01 * wb.x + v02 * wc.x + v03 * wd.x;
        float t01 = v00 * wa.y + v01 * wb.y + v02 * wc.y + v03 * wd.y;
        float t10 = v10 * wa.x + v11 * wb.x + v12 * wc.x + v13 * wd.x;
        float t11 = v10 * wa.y + v11 * wb.y + v12 * wc.y + v13 * wd.y;
        float t20 = v20 * wa.x + v21 * wb.x + v22 * wc.x + v23 * wd.x;
        float t21 = v20 * wa.y + v21 * wb.y + v22 * wc.y + v23 * wd.y;
        #pragma unroll
        for (int m = 1; m < 16; m <<= 1) {
            t00 += __shfl_xor(t00, m, 64);  t01 += __shfl_xor(t01, m, 64);
            t10 += __shfl_xor(t10, m, 64);  t11 += __shfl_xor(t11, m, 64);
            t20 += __shfl_xor(t20, m, 64);  t21 += __shfl_xor(t21, m, 64);
        }
        float sum;
        {
            float l0 = t00 + b20, l1 = t01 + b21;
            float mx = fmaxf(l0, l1);
            sum = mx + __logf(__expf(l0 - mx) + __expf(l1 - mx)) - (lb0 ? l1 : l0);
            l0 = t10 + b20; l1 = t11 + b21; mx = fmaxf(l0, l1);
            sum += mx + __logf(__expf(l0 - mx) + __expf(l1 - mx)) - (lb1 ? l1 : l0);
            l0 = t20 + b20; l1 = t21 + b21; mx = fmaxf(l0, l1);
            sum += mx + __logf(__expf(l0 - mx) + __expf(l1 - mx)) - (lb2 ? l1 : l0);
        }
        if (g + 98304 + z < NE) {
            int e3 = g + 98304 + z;
            int ln3 = L[e3], rn3 = R[e3], lb3 = label[e3];
            float4 p3 = *(const float4*)&P[ln3 * HD + sl * 4];
            float4 q3 = *(const float4*)&Q[rn3 * HD + sl * 4];
            float w0 = fmaxf(p3.x + q3.x, 0.f), w1 = fmaxf(p3.y + q3.y, 0.f);
            float w2 = fmaxf(p3.z + q3.z, 0.f), w3 = fmaxf(p3.w + q3.w, 0.f);
            float t30 = w0 * wa.x + w1 * wb.x + w2 * wc.x + w3 * wd.x;
            float t31 = w0 * wa.y + w1 * wb.y + w2 * wc.y + w3 * wd.y;
            #pragma unroll
            for (int m = 1; m < 16; m <<= 1) {
                t30 += __shfl_xor(t30, m, 64);  t31 += __shfl_xor(t31, m, 64);
            }
            float l0 = t30 + b20, l1 = t31 + b21;
            float mx = fmaxf(l0, l1);
            sum += mx + __logf(__expf(l0 - mx) + __expf(l1 - mx)) - (lb3 ? l1 : l0);
        }
        sumf = sum;
        asm volatile("" :: "v"(sumf));                 // keep every pass live
    }
    float sum = (sl == 0) ? sumf : 0.f;
    #pragma unroll
    for (int m = 1; m < 64; m <<= 1) sum += __shfl_xor(sum, m, 64);
    __shared__ float wsum[4];
    if ((tid & 63) == 0) wsum[tid >> 6] = sum;
    __syncthreads();
    if (tid == 0) partials[blockIdx.x] = wsum[0] + wsum[1] + wsum[2] + wsum[3];
}

// K4: reduce 2048 partials -> mean (unchanged)
__global__ __launch_bounds__(1024) void k_reduce(const float* __restrict__ partials, float* __restrict__ out) {
    __shared__ float sh[1024];
    int t = threadIdx.x;
    sh[t] = partials[t] + partials[t + 1024];
    __syncthreads();
    for (int s = 512; s > 0; s >>= 1) {
        if (t < s) sh[t] += sh[t + s];
        __syncthreads();
    }
    if (t == 0) out[0] = sh[0] / (float)NE;
}

extern "C" void kernel_launch(void* const* d_in, const int* in_sizes, int n_in,
                              void* d_out, int out_size, void* d_ws, size_t ws_size,
                              hipStream_t stream) {
    const float* x     = (const float*)d_in[0];
    const float* adj   = (const float*)d_in[1];
    const int*   L     = (const int*)d_in[2];
    const int*   R     = (const int*)d_in[3];
    const int*   label = (const int*)d_in[4];
    const float* W     = (const float*)d_in[5];
    const float* a1    = (const float*)d_in[6];
    const float* a2    = (const float*)d_in[7];
    const float* W1    = (const float*)d_in[8];
    const float* b1    = (const float*)d_in[9];
    const float* W2    = (const float*)d_in[10];
    const float* b2    = (const float*)d_in[11];

    char* ws = (char*)d_ws;
    float* Wh       = (float*)(ws + 0);         //  786432 B
    float* s1t      = (float*)(ws + 786432);    //   98304 B   [N][8]
    float* s2t      = (float*)(ws + 884736);    //   98304 B   [N][8]
    int*   cnt      = (int*)  (ws + 983040);    //   12288 B
    int*   nbr      = (int*)  (ws + 995328);    // 1179648 B
    float* P        = (float*)(ws + 2174976);   //  786432 B
    float* Q        = (float*)(ws + 2961408);   //  786432 B
    float* partials = (float*)(ws + 3747840);   //    8192 B

    k_stage1<<<WH_BLOCKS + NN, 256, 0, stream>>>(adj, x, W, a1, a2, nbr, cnt, Wh, s1t, s2t);
    k_attn_pq<<<NN / AROWS, 512, 0, stream>>>(Wh, s1t, s2t, nbr, cnt, W1, b1, P, Q);
    k_cls<<<K5_BLOCKS, 256, 0, stream>>>(P, Q, L, R, label, W2, b2, partials);
    k_reduce<<<1, 1024, 0, stream>>>(partials, (float*)d_out);
}

// Round 12
// 147.778 us; speedup vs baseline: 1.0078x; 1.0078x over previous
//
#include <hip/hip_runtime.h>
#include <math.h>

#define NN 3072
#define FEAT 512
#define HD 64           // 8 heads x 8 dims
#define NE 100000
#define ALPHA 0.2f
#define CAP 96          // max neighbors per row (mean ~7)
#define CAPP 97         // padded for LDS bank spread
#define AROWS 8         // rows per attn block (8 waves)
#define K5_BLOCKS 2048
#define NPRE 16         // pre-role probe replication
#define NWH 16          // wh-role probe replication

// K1a PROBE: pre role x16. One adj row per block, 4 waves x 768 cols.
// Passes perturbed by runtime-zero z (from L[0]>>31); nbr/cnt written on pass 0 only.
__global__ __launch_bounds__(256) void k_pre(const float* __restrict__ adj, const int* __restrict__ Lp,
                                             int* __restrict__ nbr, int* __restrict__ cnt) {
    __shared__ int wcnt[4];
    int i = blockIdx.x;
    int tid = threadIdx.x;
    int wid = tid >> 6, lane = tid & 63;
    int rz = (int)(((const unsigned*)Lp)[0] >> 31);       // runtime 0
    const float4* row4 = (const float4*)&adj[(size_t)i * NN];
    unsigned long long lmask = (1ull << lane) - 1ull;
    #pragma unroll 1
    for (int ps = 0; ps < NPRE; ++ps) {
        int z = rz * ps;                                  // 0, symbolic
        float4 v[3];
        #pragma unroll
        for (int c = 0; c < 3; ++c) v[c] = row4[wid * 192 + c * 64 + ((lane + z) & 63)];
        int wc = 0;
        unsigned long long masks[12];
        #pragma unroll
        for (int c = 0; c < 3; ++c) {
            #pragma unroll
            for (int k = 0; k < 4; ++k) {
                float vk = k == 0 ? v[c].x : k == 1 ? v[c].y : k == 2 ? v[c].z : v[c].w;
                unsigned long long m = __ballot(vk > 0.f);
                masks[c * 4 + k] = m;
                wc += __popcll(m);
            }
        }
        asm volatile("" :: "v"(wc));                      // keep pass live
        if (lane == 0) wcnt[wid] = wc;
        __syncthreads();
        if (ps == 0) {
            int base = 0;
            #pragma unroll
            for (int w2 = 0; w2 < 4; ++w2) if (w2 < wid) base += wcnt[w2];
            #pragma unroll
            for (int c = 0; c < 3; ++c) {
                #pragma unroll
                for (int k = 0; k < 4; ++k) {
                    unsigned long long m = masks[c * 4 + k];
                    if ((m >> lane) & 1ull) {
                        int pos = base + __popcll(m & lmask);
                        if (pos < CAP) nbr[i * CAP + pos] = wid * 768 + c * 256 + lane * 4 + k;
                    }
                    base += __popcll(m);
                }
            }
            if (tid == 0) {
                int tot = wcnt[0] + wcnt[1] + wcnt[2] + wcnt[3];
                cnt[i] = tot < CAP ? tot : CAP;
            }
        }
        __syncthreads();
    }
}

// K1b PROBE: wh role x16. 4 rows per block, K split over 4 waves, float4-over-d W loads.
// Epilogue (reduce+store) runs once on the final pass's bitwise-identical accumulators.
__global__ __launch_bounds__(256) void k_wh(const float* __restrict__ x, const float* __restrict__ W,
                                            const float* __restrict__ a1, const float* __restrict__ a2,
                                            const int* __restrict__ Lp, float* __restrict__ Wh,
                                            float* __restrict__ s1t, float* __restrict__ s2t) {
    __shared__ float xs[4][FEAT];
    __shared__ float part[4][4][HD];
    int tid = threadIdx.x;
    int wid = tid >> 6, lane = tid & 63;
    int rz = (int)(((const unsigned*)Lp)[0] >> 31);       // runtime 0
    int n0 = blockIdx.x * 4;
    int fsub = lane >> 4, h = (lane >> 1) & 7, dq = lane & 1;
    const float4* W4 = (const float4*)W;
    int base4 = h * 1024 + dq;
    int f0 = wid * (FEAT / 4);
    float4 acc0, acc1, acc2, acc3;
    #pragma unroll 1
    for (int ps = 0; ps < NWH; ++ps) {
        int z = rz * ps;
        __syncthreads();                                  // xs safe to overwrite
        for (int idx = tid; idx < 512; idx += 256) {      // stage x (perturbed index)
            int r = idx >> 7, fq = (idx + z) & 127;
            *(float4*)&xs[r][fq * 4] = ((const float4*)x)[(size_t)(n0 + r) * (FEAT / 4) + fq];
        }
        __syncthreads();
        float4 zed = {0.f, 0.f, 0.f, 0.f};
        acc0 = zed; acc1 = zed; acc2 = zed; acc3 = zed;
        #pragma unroll 4
        for (int f4 = 0; f4 < 32; ++f4) {
            int f = f0 + ((f4 * 4 + fsub + z) & 127);
            float4 w4 = W4[base4 + f * 2];
            float x0 = xs[0][f], x1 = xs[1][f], x2 = xs[2][f], x3 = xs[3][f];
            acc0.x = fmaf(x0, w4.x, acc0.x); acc0.y = fmaf(x0, w4.y, acc0.y);
            acc0.z = fmaf(x0, w4.z, acc0.z); acc0.w = fmaf(x0, w4.w, acc0.w);
            acc1.x = fmaf(x1, w4.x, acc1.x); acc1.y = fmaf(x1, w4.y, acc1.y);
            acc1.z = fmaf(x1, w4.z, acc1.z); acc1.w = fmaf(x1, w4.w, acc1.w);
            acc2.x = fmaf(x2, w4.x, acc2.x); acc2.y = fmaf(x2, w4.y, acc2.y);
            acc2.z = fmaf(x2, w4.z, acc2.z); acc2.w = fmaf(x2, w4.w, acc2.w);
            acc3.x = fmaf(x3, w4.x, acc3.x); acc3.y = fmaf(x3, w4.y, acc3.y);
            acc3.z = fmaf(x3, w4.z, acc3.z); acc3.w = fmaf(x3, w4.w, acc3.w);
        }
        asm volatile("" :: "v"(acc0.x), "v"(acc0.y), "v"(acc0.z), "v"(acc0.w));
        asm volatile("" :: "v"(acc1.x), "v"(acc1.y), "v"(acc1.z), "v"(acc1.w));
        asm volatile("" :: "v"(acc2.x), "v"(acc2.y), "v"(acc2.z), "v"(acc2.w));
        asm volatile("" :: "v"(acc3.x), "v"(acc3.y), "v"(acc3.z), "v"(acc3.w));
    }
    #define RED4(A) \
        A.x += __shfl_xor(A.x, 16, 64); A.x += __shfl_xor(A.x, 32, 64); \
        A.y += __shfl_xor(A.y, 16, 64); A.y += __shfl_xor(A.y, 32, 64); \
        A.z += __shfl_xor(A.z, 16, 64); A.z += __shfl_xor(A.z, 32, 64); \
        A.w += __shfl_xor(A.w, 16, 64); A.w += __shfl_xor(A.w, 32, 64);
    RED4(acc0) RED4(acc1) RED4(acc2) RED4(acc3)
    #undef RED4
    if (fsub == 0) {
        int o = h * 8 + dq * 4;
        *(float4*)&part[wid][0][o] = acc0;
        *(float4*)&part[wid][1][o] = acc1;
        *(float4*)&part[wid][2][o] = acc2;
        *(float4*)&part[wid][3][o] = acc3;
    }
    __syncthreads();
    int n = n0 + wid;
    float v = part[0][wid][lane] + part[1][wid][lane] + part[2][wid][lane] + part[3][wid][lane];
    Wh[n * HD + lane] = v;
    float t1 = v * a1[lane];
    float t2 = v * a2[lane];
    for (int m = 1; m < 8; m <<= 1) {
        t1 += __shfl_xor(t1, m, 64);
        t2 += __shfl_xor(t2, m, 64);
    }
    if ((lane & 7) == 0) {
        int h2 = lane >> 3;
        s1t[n * 8 + h2] = t1;
        s2t[n * 8 + h2] = t2;
    }
}

// K2: attention + ELU + fused P/Q (byte-identical to round 10).
__global__ __launch_bounds__(512) void k_attn_pq(const float* __restrict__ Wh, const float* __restrict__ s1t,
                                                 const float* __restrict__ s2t, const int* __restrict__ nbr,
                                                 const int* __restrict__ cnt, const float* __restrict__ W1,
                                                 const float* __restrict__ b1, float* __restrict__ P,
                                                 float* __restrict__ Q) {
    __shared__ float W1s[2 * HD][HD];
    __shared__ int   jbuf[AROWS][CAP];
    __shared__ float ebuf[AROWS][8][CAPP];
    __shared__ float es[AROWS][HD];
    int tid = threadIdx.x;
    int wid = tid >> 6;
    int lane = tid & 63;
    int i = blockIdx.x * AROWS + wid;
    int h = lane >> 3, d = lane & 7;
    int ni = cnt[i];
    float s1i = s1t[i * 8 + h];
    for (int k = lane; k < CAP; k += 64)
        if (k < ni) jbuf[wid][k] = nbr[i * CAP + k];
    for (int idx = tid; idx < 2048; idx += 512)
        ((float4*)W1s)[idx] = ((const float4*)W1)[idx];
    __syncthreads();
    float mloc = -INFINITY;
    for (int k = d; k < ni; k += 8) {
        int j = jbuf[wid][k];
        float ev = s1i + s2t[j * 8 + h];
        ev = ev > 0.f ? ev : ALPHA * ev;
        ebuf[wid][h][k] = ev;
        mloc = fmaxf(mloc, ev);
    }
    mloc = fmaxf(mloc, __shfl_xor(mloc, 1, 8));
    mloc = fmaxf(mloc, __shfl_xor(mloc, 2, 8));
    mloc = fmaxf(mloc, __shfl_xor(mloc, 4, 8));
    __syncthreads();
    float denom = 0.f, acc = 0.f;
    for (int k = 0; k < ni; ++k) {
        float p = __expf(ebuf[wid][h][k] - mloc);
        denom += p;
        acc = fmaf(p, Wh[jbuf[wid][k] * HD + lane], acc);
    }
    float o = acc / denom;
    o = o > 0.f ? o : expm1f(o);
    es[wid][lane] = o;
    __syncthreads();
    float p = b1[lane], q = 0.f;
    #pragma unroll 8
    for (int k = 0; k < HD; ++k) {
        float e = es[wid][k];
        p = fmaf(e, W1s[k][lane], p);
        q = fmaf(e, W1s[HD + k][lane], q);
    }
    P[i * HD + lane] = p;
    Q[i * HD + lane] = q;
}

// K3: edge classifier (byte-identical to round 10).
__global__ __launch_bounds__(256) void k_cls(const float* __restrict__ P, const float* __restrict__ Q,
                                             const int* __restrict__ L, const int* __restrict__ R,
                                             const int* __restrict__ label, const float* __restrict__ W2,
                                             const float* __restrict__ b2, float* __restrict__ partials) {
    int tid = threadIdx.x;
    int sl = tid & 15;
    int g = (blockIdx.x * 256 + tid) >> 4;
    float2 wa = *(const float2*)&W2[(sl * 4 + 0) * 2];
    float2 wb = *(const float2*)&W2[(sl * 4 + 1) * 2];
    float2 wc = *(const float2*)&W2[(sl * 4 + 2) * 2];
    float2 wd = *(const float2*)&W2[(sl * 4 + 3) * 2];
    float b20 = b2[0], b21 = b2[1];

    int e0 = g, e1 = g + 32768, e2 = g + 65536;
    int ln0 = L[e0], rn0 = R[e0], lb0 = label[e0];
    int ln1 = L[e1], rn1 = R[e1], lb1 = label[e1];
    int ln2 = L[e2], rn2 = R[e2], lb2 = label[e2];
    float4 p0 = *(const float4*)&P[ln0 * HD + sl * 4];
    float4 q0 = *(const float4*)&Q[rn0 * HD + sl * 4];
    float4 p1 = *(const float4*)&P[ln1 * HD + sl * 4];
    float4 q1 = *(const float4*)&Q[rn1 * HD + sl * 4];
    float4 p2 = *(const float4*)&P[ln2 * HD + sl * 4];
    float4 q2 = *(const float4*)&Q[rn2 * HD + sl * 4];

    float v00 = fmaxf(p0.x + q0.x, 0.f), v01 = fmaxf(p0.y + q0.y, 0.f);
    float v02 = fmaxf(p0.z + q0.z, 0.f), v03 = fmaxf(p0.w + q0.w, 0.f);
    float v10 = fmaxf(p1.x + q1.x, 0.f), v11 = fmaxf(p1.y + q1.y, 0.f);
    float v12 = fmaxf(p1.z + q1.z, 0.f), v13 = fmaxf(p1.w + q1.w, 0.f);
    float v20 = fmaxf(p2.x + q2.x, 0.f), v21 = fmaxf(p2.y + q2.y, 0.f);
    float v22 = fmaxf(p2.z + q2.z, 0.f), v23 = fmaxf(p2.w + q2.w, 0.f);

    float t00 = v00 * wa.x + v01 * wb.x + v02 * wc.x + v03 * wd.x;
    float t01 = v00 * wa.y + v01 * wb.y + v02 * wc.y + v03 * wd.y;
    float t10 = v10 * wa.x + v11 * wb.x + v12 * wc.x + v13 * wd.x;
    float t11 = v10 * wa.y + v11 * wb.y + v12 * wc.y + v13 * wd.y;
    float t20 = v20 * wa.x + v21 * wb.x + v22 * wc.x + v23 * wd.x;
    float t21 = v20 * wa.y + v21 * wb.y + v22 * wc.y + v23 * wd.y;
    #pragma unroll
    for (int m = 1; m < 16; m <<= 1) {
        t00 += __shfl_xor(t00, m, 64);  t01 += __shfl_xor(t01, m, 64);
        t10 += __shfl_xor(t10, m, 64);  t11 += __shfl_xor(t11, m, 64);
        t20 += __shfl_xor(t20, m, 64);  t21 += __shfl_xor(t21, m, 64);
    }
    float sum;
    {
        float l0 = t00 + b20, l1 = t01 + b21;
        float mx = fmaxf(l0, l1);
        sum = mx + __logf(__expf(l0 - mx) + __expf(l1 - mx)) - (lb0 ? l1 : l0);
        l0 = t10 + b20; l1 = t11 + b21; mx = fmaxf(l0, l1);
        sum += mx + __logf(__expf(l0 - mx) + __expf(l1 - mx)) - (lb1 ? l1 : l0);
        l0 = t20 + b20; l1 = t21 + b21; mx = fmaxf(l0, l1);
        sum += mx + __logf(__expf(l0 - mx) + __expf(l1 - mx)) - (lb2 ? l1 : l0);
    }
    if (g + 98304 < NE) {
        int e3 = g + 98304;
        int ln3 = L[e3], rn3 = R[e3], lb3 = label[e3];
        float4 p3 = *(const float4*)&P[ln3 * HD + sl * 4];
        float4 q3 = *(const float4*)&Q[rn3 * HD + sl * 4];
        float w0 = fmaxf(p3.x + q3.x, 0.f), w1 = fmaxf(p3.y + q3.y, 0.f);
        float w2 = fmaxf(p3.z + q3.z, 0.f), w3 = fmaxf(p3.w + q3.w, 0.f);
        float t30 = w0 * wa.x + w1 * wb.x + w2 * wc.x + w3 * wd.x;
        float t31 = w0 * wa.y + w1 * wb.y + w2 * wc.y + w3 * wd.y;
        #pragma unroll
        for (int m = 1; m < 16; m <<= 1) {
            t30 += __shfl_xor(t30, m, 64);  t31 += __shfl_xor(t31, m, 64);
        }
        float l0 = t30 + b20, l1 = t31 + b21;
        float mx = fmaxf(l0, l1);
        sum += mx + __logf(__expf(l0 - mx) + __expf(l1 - mx)) - (lb3 ? l1 : l0);
    }
    sum = (sl == 0) ? sum : 0.f;
    #pragma unroll
    for (int m = 1; m < 64; m <<= 1) sum += __shfl_xor(sum, m, 64);
    __shared__ float wsum[4];
    if ((tid & 63) == 0) wsum[tid >> 6] = sum;
    __syncthreads();
    if (tid == 0) partials[blockIdx.x] = wsum[0] + wsum[1] + wsum[2] + wsum[3];
}

// K4: reduce 2048 partials -> mean (unchanged)
__global__ __launch_bounds__(1024) void k_reduce(const float* __restrict__ partials, float* __restrict__ out) {
    __shared__ float sh[1024];
    int t = threadIdx.x;
    sh[t] = partials[t] + partials[t + 1024];
    __syncthreads();
    for (int s = 512; s > 0; s >>= 1) {
        if (t < s) sh[t] += sh[t + s];
        __syncthreads();
    }
    if (t == 0) out[0] = sh[0] / (float)NE;
}

extern "C" void kernel_launch(void* const* d_in, const int* in_sizes, int n_in,
                              void* d_out, int out_size, void* d_ws, size_t ws_size,
                              hipStream_t stream) {
    const float* x     = (const float*)d_in[0];
    const float* adj   = (const float*)d_in[1];
    const int*   L     = (const int*)d_in[2];
    const int*   R     = (const int*)d_in[3];
    const int*   label = (const int*)d_in[4];
    const float* W     = (const float*)d_in[5];
    const float* a1    = (const float*)d_in[6];
    const float* a2    = (const float*)d_in[7];
    const float* W1    = (const float*)d_in[8];
    const float* b1    = (const float*)d_in[9];
    const float* W2    = (const float*)d_in[10];
    const float* b2    = (const float*)d_in[11];

    char* ws = (char*)d_ws;
    float* Wh       = (float*)(ws + 0);         //  786432 B
    float* s1t      = (float*)(ws + 786432);    //   98304 B   [N][8]
    float* s2t      = (float*)(ws + 884736);    //   98304 B   [N][8]
    int*   cnt      = (int*)  (ws + 983040);    //   12288 B
    int*   nbr      = (int*)  (ws + 995328);    // 1179648 B
    float* P        = (float*)(ws + 2174976);   //  786432 B
    float* Q        = (float*)(ws + 2961408);   //  786432 B
    float* partials = (float*)(ws + 3747840);   //    8192 B

    k_pre<<<NN, 256, 0, stream>>>(adj, L, nbr, cnt);
    k_wh<<<NN / 4, 256, 0, stream>>>(x, W, a1, a2, L, Wh, s1t, s2t);
    k_attn_pq<<<NN / AROWS, 512, 0, stream>>>(Wh, s1t, s2t, nbr, cnt, W1, b1, P, Q);
    k_cls<<<K5_BLOCKS, 256, 0, stream>>>(P, Q, L, R, label, W2, b2, partials);
    k_reduce<<<1, 1024, 0, stream>>>(partials, (float*)d_out);
}

// Round 13
// 34.861 us; speedup vs baseline: 4.2723x; 4.2391x over previous
//
#include <hip/hip_runtime.h>
#include <math.h>

#define NN 3072
#define FEAT 512
#define HD 64           // 8 heads x 8 dims
#define NE 100000
#define ALPHA 0.2f
#define CAP 96          // max neighbors per row (mean ~7)
#define CAPP 97         // padded for LDS bank spread
#define AROWS 8         // rows per attn block (8 waves)
#define WH_BLOCKS 384   // wh role: 8 rows per block
#define K5_BLOCKS 2048

// K1 (fused, 512 threads/block, 1920 blocks):
//   b < 384 : wh role — 8 rows, K split over 8 waves (16 f4-iters each),
//             32 FMA per 16B W load (~80% FMA issue density).
//   b >= 384: pre role — 2 adj rows per block (4 waves each), same write pattern as R10.
__global__ __launch_bounds__(512) void k_stage1(const float* __restrict__ adj, const float* __restrict__ x,
                                                const float* __restrict__ W, const float* __restrict__ a1,
                                                const float* __restrict__ a2, int* __restrict__ nbr,
                                                int* __restrict__ cnt, float* __restrict__ Wh,
                                                float* __restrict__ s1t, float* __restrict__ s2t) {
    __shared__ float xs[8][FEAT];       // 16 KB (wh)
    __shared__ float part[8][8][HD];    // 16 KB (wh)
    __shared__ int   wcnt[2][4];        // (pre)
    int b = blockIdx.x;
    int tid = threadIdx.x;
    int wid = tid >> 6, lane = tid & 63;

    if (b >= WH_BLOCKS) {
        // ---- pre role: rows (b-384)*2 + sub, 4 waves per row ----
        int sub = wid >> 2;                                   // 0..1
        int w4i = wid & 3;                                    // 0..3
        int i = (b - WH_BLOCKS) * 2 + sub;
        const float4* row4 = (const float4*)&adj[(size_t)i * NN];
        float4 v[3];
        #pragma unroll
        for (int c = 0; c < 3; ++c) v[c] = row4[w4i * 192 + c * 64 + lane];
        unsigned long long lmask = (1ull << lane) - 1ull;
        int wc = 0;
        unsigned long long masks[12];
        #pragma unroll
        for (int c = 0; c < 3; ++c) {
            #pragma unroll
            for (int k = 0; k < 4; ++k) {
                float vk = k == 0 ? v[c].x : k == 1 ? v[c].y : k == 2 ? v[c].z : v[c].w;
                unsigned long long m = __ballot(vk > 0.f);
                masks[c * 4 + k] = m;
                wc += __popcll(m);
            }
        }
        if (lane == 0) wcnt[sub][w4i] = wc;
        __syncthreads();
        int base = 0;
        #pragma unroll
        for (int w2 = 0; w2 < 4; ++w2) if (w2 < w4i) base += wcnt[sub][w2];
        #pragma unroll
        for (int c = 0; c < 3; ++c) {
            #pragma unroll
            for (int k = 0; k < 4; ++k) {
                unsigned long long m = masks[c * 4 + k];
                if ((m >> lane) & 1ull) {
                    int pos = base + __popcll(m & lmask);
                    if (pos < CAP) nbr[i * CAP + pos] = w4i * 768 + c * 256 + lane * 4 + k;
                }
                base += __popcll(m);
            }
        }
        if (w4i == 0 && lane == 0) {
            int tot = wcnt[sub][0] + wcnt[sub][1] + wcnt[sub][2] + wcnt[sub][3];
            cnt[i] = tot < CAP ? tot : CAP;
        }
    } else {
        // ---- wh role: rows n0..n0+7, K split over 8 waves ----
        int n0 = b * 8;
        #pragma unroll
        for (int t = 0; t < 2; ++t) {                         // stage 8 rows of x
            int idx = tid + t * 512;                          // 1024 float4 total
            int r = idx >> 7, fq = idx & 127;
            *(float4*)&xs[r][fq * 4] = ((const float4*)x)[(size_t)(n0 + r) * (FEAT / 4) + fq];
        }
        __syncthreads();
        int fsub = lane >> 4, h = (lane >> 1) & 7, dq = lane & 1;
        const float4* W4 = (const float4*)W;
        int base4 = h * 1024 + dq;                            // + f*2 -> W[h][f][dq*4..+3]
        int f0 = wid * (FEAT / 8);                            // 64 per wave
        float4 a0 = {0,0,0,0}, a1v = a0, a2v = a0, a3 = a0, a4 = a0, a5 = a0, a6 = a0, a7 = a0;
        #pragma unroll 4
        for (int f4 = 0; f4 < 16; ++f4) {
            int f = f0 + f4 * 4 + fsub;
            float4 w4 = W4[base4 + f * 2];                    // 16B, wave = 8x128B segments
            float x0 = xs[0][f], x1 = xs[1][f], x2 = xs[2][f], x3 = xs[3][f];
            float x4 = xs[4][f], x5 = xs[5][f], x6 = xs[6][f], x7 = xs[7][f];
            a0.x = fmaf(x0, w4.x, a0.x); a0.y = fmaf(x0, w4.y, a0.y);
            a0.z = fmaf(x0, w4.z, a0.z); a0.w = fmaf(x0, w4.w, a0.w);
            a1v.x = fmaf(x1, w4.x, a1v.x); a1v.y = fmaf(x1, w4.y, a1v.y);
            a1v.z = fmaf(x1, w4.z, a1v.z); a1v.w = fmaf(x1, w4.w, a1v.w);
            a2v.x = fmaf(x2, w4.x, a2v.x); a2v.y = fmaf(x2, w4.y, a2v.y);
            a2v.z = fmaf(x2, w4.z, a2v.z); a2v.w = fmaf(x2, w4.w, a2v.w);
            a3.x = fmaf(x3, w4.x, a3.x); a3.y = fmaf(x3, w4.y, a3.y);
            a3.z = fmaf(x3, w4.z, a3.z); a3.w = fmaf(x3, w4.w, a3.w);
            a4.x = fmaf(x4, w4.x, a4.x); a4.y = fmaf(x4, w4.y, a4.y);
            a4.z = fmaf(x4, w4.z, a4.z); a4.w = fmaf(x4, w4.w, a4.w);
            a5.x = fmaf(x5, w4.x, a5.x); a5.y = fmaf(x5, w4.y, a5.y);
            a5.z = fmaf(x5, w4.z, a5.z); a5.w = fmaf(x5, w4.w, a5.w);
            a6.x = fmaf(x6, w4.x, a6.x); a6.y = fmaf(x6, w4.y, a6.y);
            a6.z = fmaf(x6, w4.z, a6.z); a6.w = fmaf(x6, w4.w, a6.w);
            a7.x = fmaf(x7, w4.x, a7.x); a7.y = fmaf(x7, w4.y, a7.y);
            a7.z = fmaf(x7, w4.z, a7.z); a7.w = fmaf(x7, w4.w, a7.w);
        }
        // butterfly over 4 fsub groups (fixed order)
        #define RED4(A) \
            A.x += __shfl_xor(A.x, 16, 64); A.x += __shfl_xor(A.x, 32, 64); \
            A.y += __shfl_xor(A.y, 16, 64); A.y += __shfl_xor(A.y, 32, 64); \
            A.z += __shfl_xor(A.z, 16, 64); A.z += __shfl_xor(A.z, 32, 64); \
            A.w += __shfl_xor(A.w, 16, 64); A.w += __shfl_xor(A.w, 32, 64);
        RED4(a0) RED4(a1v) RED4(a2v) RED4(a3) RED4(a4) RED4(a5) RED4(a6) RED4(a7)
        #undef RED4
        if (fsub == 0) {
            int o = h * 8 + dq * 4;
            *(float4*)&part[wid][0][o] = a0;
            *(float4*)&part[wid][1][o] = a1v;
            *(float4*)&part[wid][2][o] = a2v;
            *(float4*)&part[wid][3][o] = a3;
            *(float4*)&part[wid][4][o] = a4;
            *(float4*)&part[wid][5][o] = a5;
            *(float4*)&part[wid][6][o] = a6;
            *(float4*)&part[wid][7][o] = a7;
        }
        __syncthreads();
        int n = n0 + wid;                                     // wave wid finalizes row n0+wid
        float v = 0.f;
        #pragma unroll
        for (int w2 = 0; w2 < 8; ++w2) v += part[w2][wid][lane];   // fixed order
        Wh[n * HD + lane] = v;
        float t1 = v * a1[lane];
        float t2 = v * a2[lane];
        for (int m = 1; m < 8; m <<= 1) {
            t1 += __shfl_xor(t1, m, 64);
            t2 += __shfl_xor(t2, m, 64);
        }
        if ((lane & 7) == 0) {
            int h2 = lane >> 3;
            s1t[n * 8 + h2] = t1;
            s2t[n * 8 + h2] = t2;
        }
    }
}

// K2: attention + ELU + fused P/Q. 8 waves = 8 rows per block; W1 staged in LDS.
//     Gather loop 2-way unrolled: 2 Wh gathers in flight (dual accumulator).
__global__ __launch_bounds__(512) void k_attn_pq(const float* __restrict__ Wh, const float* __restrict__ s1t,
                                                 const float* __restrict__ s2t, const int* __restrict__ nbr,
                                                 const int* __restrict__ cnt, const float* __restrict__ W1,
                                                 const float* __restrict__ b1, float* __restrict__ P,
                                                 float* __restrict__ Q) {
    __shared__ float W1s[2 * HD][HD];
    __shared__ int   jbuf[AROWS][CAP];
    __shared__ float ebuf[AROWS][8][CAPP];
    __shared__ float es[AROWS][HD];
    int tid = threadIdx.x;
    int wid = tid >> 6;
    int lane = tid & 63;
    int i = blockIdx.x * AROWS + wid;
    int h = lane >> 3, d = lane & 7;
    int ni = cnt[i];
    float s1i = s1t[i * 8 + h];
    for (int k = lane; k < CAP; k += 64)
        if (k < ni) jbuf[wid][k] = nbr[i * CAP + k];
    for (int idx = tid; idx < 2048; idx += 512)
        ((float4*)W1s)[idx] = ((const float4*)W1)[idx];
    __syncthreads();
    float mloc = -INFINITY;
    for (int k = d; k < ni; k += 8) {
        int j = jbuf[wid][k];
        float ev = s1i + s2t[j * 8 + h];
        ev = ev > 0.f ? ev : ALPHA * ev;
        ebuf[wid][h][k] = ev;
        mloc = fmaxf(mloc, ev);
    }
    mloc = fmaxf(mloc, __shfl_xor(mloc, 1, 8));
    mloc = fmaxf(mloc, __shfl_xor(mloc, 2, 8));
    mloc = fmaxf(mloc, __shfl_xor(mloc, 4, 8));
    __syncthreads();
    float den0 = 0.f, den1 = 0.f, ac0 = 0.f, ac1 = 0.f;
    int k = 0;
    for (; k + 1 < ni; k += 2) {                   // 2 gathers in flight
        int j0 = jbuf[wid][k], j1 = jbuf[wid][k + 1];
        float p0 = __expf(ebuf[wid][h][k] - mloc);
        float p1 = __expf(ebuf[wid][h][k + 1] - mloc);
        float w0 = Wh[j0 * HD + lane], w1 = Wh[j1 * HD + lane];
        den0 += p0; den1 += p1;
        ac0 = fmaf(p0, w0, ac0);
        ac1 = fmaf(p1, w1, ac1);
    }
    if (k < ni) {
        float p0 = __expf(ebuf[wid][h][k] - mloc);
        den0 += p0;
        ac0 = fmaf(p0, Wh[jbuf[wid][k] * HD + lane], ac0);
    }
    float o = (ac0 + ac1) / (den0 + den1);
    o = o > 0.f ? o : expm1f(o);
    es[wid][lane] = o;
    __syncthreads();
    float p = b1[lane], q = 0.f;
    #pragma unroll 8
    for (int kk = 0; kk < HD; ++kk) {
        float e = es[wid][kk];
        p = fmaf(e, W1s[kk][lane], p);
        q = fmaf(e, W1s[HD + kk][lane], q);
    }
    P[i * HD + lane] = p;
    Q[i * HD + lane] = q;
}

// K3: 16 lanes per edge; 3 edges + tail processed concurrently; branchless lse.
__global__ __launch_bounds__(256) void k_cls(const float* __restrict__ P, const float* __restrict__ Q,
                                             const int* __restrict__ L, const int* __restrict__ R,
                                             const int* __restrict__ label, const float* __restrict__ W2,
                                             const float* __restrict__ b2, float* __restrict__ partials) {
    int tid = threadIdx.x;
    int sl = tid & 15;
    int g = (blockIdx.x * 256 + tid) >> 4;
    float2 wa = *(const float2*)&W2[(sl * 4 + 0) * 2];
    float2 wb = *(const float2*)&W2[(sl * 4 + 1) * 2];
    float2 wc = *(const float2*)&W2[(sl * 4 + 2) * 2];
    float2 wd = *(const float2*)&W2[(sl * 4 + 3) * 2];
    float b20 = b2[0], b21 = b2[1];

    int e0 = g, e1 = g + 32768, e2 = g + 65536;
    int ln0 = L[e0], rn0 = R[e0], lb0 = label[e0];
    int ln1 = L[e1], rn1 = R[e1], lb1 = label[e1];
    int ln2 = L[e2], rn2 = R[e2], lb2 = label[e2];
    float4 p0 = *(const float4*)&P[ln0 * HD + sl * 4];
    float4 q0 = *(const float4*)&Q[rn0 * HD + sl * 4];
    float4 p1 = *(const float4*)&P[ln1 * HD + sl * 4];
    float4 q1 = *(const float4*)&Q[rn1 * HD + sl * 4];
    float4 p2 = *(const float4*)&P[ln2 * HD + sl * 4];
    float4 q2 = *(const float4*)&Q[rn2 * HD + sl * 4];

    float v00 = fmaxf(p0.x + q0.x, 0.f), v01 = fmaxf(p0.y + q0.y, 0.f);
    float v02 = fmaxf(p0.z + q0.z, 0.f), v03 = fmaxf(p0.w + q0.w, 0.f);
    float v10 = fmaxf(p1.x + q1.x, 0.f), v11 = fmaxf(p1.y + q1.y, 0.f);
    float v12 = fmaxf(p1.z + q1.z, 0.f), v13 = fmaxf(p1.w + q1.w, 0.f);
    float v20 = fmaxf(p2.x + q2.x, 0.f), v21 = fmaxf(p2.y + q2.y, 0.f);
    float v22 = fmaxf(p2.z + q2.z, 0.f), v23 = fmaxf(p2.w + q2.w, 0.f);

    float t00 = v00 * wa.x + v01 * wb.x + v02 * wc.x + v03 * wd.x;
    float t01 = v00 * wa.y + v01 * wb.y + v02 * wc.y + v03 * wd.y;
    float t10 = v10 * wa.x + v11 * wb.x + v12 * wc.x + v13 * wd.x;
    float t11 = v10 * wa.y + v11 * wb.y + v12 * wc.y + v13 * wd.y;
    float t20 = v20 * wa.x + v21 * wb.x + v22 * wc.x + v23 * wd.x;
    float t21 = v20 * wa.y + v21 * wb.y + v22 * wc.y + v23 * wd.y;
    #pragma unroll
    for (int m = 1; m < 16; m <<= 1) {
        t00 += __shfl_xor(t00, m, 64);  t01 += __shfl_xor(t01, m, 64);
        t10 += __shfl_xor(t10, m, 64);  t11 += __shfl_xor(t11, m, 64);
        t20 += __shfl_xor(t20, m, 64);  t21 += __shfl_xor(t21, m, 64);
    }
    float sum;
    {
        float l0 = t00 + b20, l1 = t01 + b21;
        float mx = fmaxf(l0, l1);
        sum = mx + __logf(__expf(l0 - mx) + __expf(l1 - mx)) - (lb0 ? l1 : l0);
        l0 = t10 + b20; l1 = t11 + b21; mx = fmaxf(l0, l1);
        sum += mx + __logf(__expf(l0 - mx) + __expf(l1 - mx)) - (lb1 ? l1 : l0);
        l0 = t20 + b20; l1 = t21 + b21; mx = fmaxf(l0, l1);
        sum += mx + __logf(__expf(l0 - mx) + __expf(l1 - mx)) - (lb2 ? l1 : l0);
    }
    if (g + 98304 < NE) {
        int e3 = g + 98304;
        int ln3 = L[e3], rn3 = R[e3], lb3 = label[e3];
        float4 p3 = *(const float4*)&P[ln3 * HD + sl * 4];
        float4 q3 = *(const float4*)&Q[rn3 * HD + sl * 4];
        float w0 = fmaxf(p3.x + q3.x, 0.f), w1 = fmaxf(p3.y + q3.y, 0.f);
        float w2 = fmaxf(p3.z + q3.z, 0.f), w3 = fmaxf(p3.w + q3.w, 0.f);
        float t30 = w0 * wa.x + w1 * wb.x + w2 * wc.x + w3 * wd.x;
        float t31 = w0 * wa.y + w1 * wb.y + w2 * wc.y + w3 * wd.y;
        #pragma unroll
        for (int m = 1; m < 16; m <<= 1) {
            t30 += __shfl_xor(t30, m, 64);  t31 += __shfl_xor(t31, m, 64);
        }
        float l0 = t30 + b20, l1 = t31 + b21;
        float mx = fmaxf(l0, l1);
        sum += mx + __logf(__expf(l0 - mx) + __expf(l1 - mx)) - (lb3 ? l1 : l0);
    }
    sum = (sl == 0) ? sum : 0.f;
    #pragma unroll
    for (int m = 1; m < 64; m <<= 1) sum += __shfl_xor(sum, m, 64);
    __shared__ float wsum[4];
    if ((tid & 63) == 0) wsum[tid >> 6] = sum;
    __syncthreads();
    if (tid == 0) partials[blockIdx.x] = wsum[0] + wsum[1] + wsum[2] + wsum[3];
}

// K4: reduce 2048 partials -> mean
__global__ __launch_bounds__(1024) void k_reduce(const float* __restrict__ partials, float* __restrict__ out) {
    __shared__ float sh[1024];
    int t = threadIdx.x;
    sh[t] = partials[t] + partials[t + 1024];
    __syncthreads();
    for (int s = 512; s > 0; s >>= 1) {
        if (t < s) sh[t] += sh[t + s];
        __syncthreads();
    }
    if (t == 0) out[0] = sh[0] / (float)NE;
}

extern "C" void kernel_launch(void* const* d_in, const int* in_sizes, int n_in,
                              void* d_out, int out_size, void* d_ws, size_t ws_size,
                              hipStream_t stream) {
    const float* x     = (const float*)d_in[0];
    const float* adj   = (const float*)d_in[1];
    const int*   L     = (const int*)d_in[2];
    const int*   R     = (const int*)d_in[3];
    const int*   label = (const int*)d_in[4];
    const float* W     = (const float*)d_in[5];
    const float* a1    = (const float*)d_in[6];
    const float* a2    = (const float*)d_in[7];
    const float* W1    = (const float*)d_in[8];
    const float* b1    = (const float*)d_in[9];
    const float* W2    = (const float*)d_in[10];
    const float* b2    = (const float*)d_in[11];

    char* ws = (char*)d_ws;
    float* Wh       = (float*)(ws + 0);         //  786432 B
    float* s1t      = (float*)(ws + 786432);    //   98304 B   [N][8]
    float* s2t      = (float*)(ws + 884736);    //   98304 B   [N][8]
    int*   cnt      = (int*)  (ws + 983040);    //   12288 B
    int*   nbr      = (int*)  (ws + 995328);    // 1179648 B
    float* P        = (float*)(ws + 2174976);   //  786432 B
    float* Q        = (float*)(ws + 2961408);   //  786432 B
    float* partials = (float*)(ws + 3747840);   //    8192 B

    k_stage1<<<WH_BLOCKS + NN / 2, 512, 0, stream>>>(adj, x, W, a1, a2, nbr, cnt, Wh, s1t, s2t);
    k_attn_pq<<<NN / AROWS, 512, 0, stream>>>(Wh, s1t, s2t, nbr, cnt, W1, b1, P, Q);
    k_cls<<<K5_BLOCKS, 256, 0, stream>>>(P, Q, L, R, label, W2, b2, partials);
    k_reduce<<<1, 1024, 0, stream>>>(partials, (float*)d_out);
}